// Round 5
// baseline (10591.733 us; speedup 1.0000x reference)
//
#include <hip/hip_runtime.h>
#include <hip/hip_bf16.h>
#include <cmath>

using bf16 = __hip_bfloat16;

#define THW 25088           // tokens per batch (T*H*W)
#define CH_ROWS 25088       // 256 windows * 98 tokens per chunk (1 batch)
#define SCALE_QK 0.17677669529663687f

static __device__ __forceinline__ float b2f(bf16 v) { return __bfloat162float(v); }
static __device__ __forceinline__ bf16 f2b(float v) { return __float2bfloat16(v); }

// dtype-agnostic external input read: flag=1 -> bf16, flag=0 -> fp32
static __device__ __forceinline__ float ldin(const void* p, size_t i, int isb) {
  return isb ? b2f(((const bf16*)p)[i]) : ((const float*)p)[i];
}
static __device__ __forceinline__ void stout(void* p, size_t i, float v, int isb) {
  if (isb) ((bf16*)p)[i] = f2b(v); else ((float*)p)[i] = v;
}

// ---------------- input-dtype detection: norm1_g[0] == 1.0 ----------------
__global__ void detect_k(const void* g1, int* flag) {
  unsigned int u = *(const unsigned int*)g1;
  *flag = (u == 0x3F803F80u) ? 1 : 0;   // packed bf16 ones vs fp32 1.0
}

// ---------------- LN1 + cyclic shift + window partition (scalar) ----------------
__global__ __launch_bounds__(256) void ln1_s(const void* __restrict__ x,
    const void* __restrict__ g, const void* __restrict__ bt, bf16* __restrict__ xw,
    int row_base, const int* __restrict__ dflag) {
  int isb = *dflag;
  int gl = blockIdx.x * 256 + threadIdx.x;
  if (gl >= CH_ROWS) return;
  int gid = gl + row_base;
  int b_ = gid / 98, n = gid - b_ * 98;
  int batch = b_ >> 8, widx = b_ & 255;
  int tw = widx >> 6, hw = (widx >> 3) & 7, ww = widx & 7;
  int ti = n / 49, rr = n - ti * 49, hi = rr / 7, wi = rr - hi * 7;
  int t = (tw * 2 + ti + 1) & 7;
  int h = hw * 7 + hi + 3; if (h >= 56) h -= 56;
  int w = ww * 7 + wi + 3; if (w >= 56) w -= 56;
  size_t src = ((size_t)batch * THW + (t * 56 + h) * 56 + w) * 128;
  float s = 0.f, ss = 0.f;
  for (int c = 0; c < 128; c++) { float v = ldin(x, src + c, isb); s += v; ss += v * v; }
  float mu = s * (1.f / 128.f);
  float var = ss * (1.f / 128.f) - mu * mu;
  float rs = rsqrtf(var + 1e-5f);
  bf16* dst = xw + (size_t)gl * 128;
  for (int c = 0; c < 128; c++) {
    float v = (ldin(x, src + c, isb) - mu) * rs * ldin(g, c, isb) + ldin(bt, c, isb);
    dst[c] = f2b(v);
  }
}

// ---------------- LN2 (fp32 internal in, bf16 internal out) ----------------
__global__ __launch_bounds__(256) void ln2_s(const float* __restrict__ xm,
    const void* __restrict__ g, const void* __restrict__ bt, bf16* __restrict__ out,
    const int* __restrict__ dflag) {
  int isb = *dflag;
  int gl = blockIdx.x * 256 + threadIdx.x;
  if (gl >= CH_ROWS) return;
  const float* src = xm + (size_t)gl * 128;
  float s = 0.f, ss = 0.f;
  for (int c = 0; c < 128; c++) { float v = src[c]; s += v; ss += v * v; }
  float mu = s * (1.f / 128.f);
  float var = ss * (1.f / 128.f) - mu * mu;
  float rs = rsqrtf(var + 1e-5f);
  bf16* dst = out + (size_t)gl * 128;
  for (int c = 0; c < 128; c++)
    dst[c] = f2b((src[c] - mu) * rs * ldin(g, c, isb) + ldin(bt, c, isb));
}

// ---------------- scalar GEMM: C = A[M][K] @ B[K][N] + bias ----------------
// A is internal bf16. B/bias are EXTERNAL (dtype via flag).
// EPI: 0=store bf16 internal, 1=proj scatter (+x residual -> fp32 xmid),
//      2=GELU store bf16 internal, 3=fp32 residual -> EXTERNAL out
template<int EPI, int K, int N>
__global__ __launch_bounds__(256) void gemm_s(const bf16* __restrict__ A,
    const void* __restrict__ B, const void* __restrict__ bias,
    bf16* __restrict__ out_b, const void* __restrict__ resid_x,
    const float* __restrict__ resid_f, float* __restrict__ out_f,
    void* __restrict__ out_ext, int row_base, int tok_base,
    const int* __restrict__ dflag) {
  int isb = *dflag;
  int idx = blockIdx.x * 256 + threadIdx.x;
  int row = idx / N, col = idx - row * N;
  if (row >= CH_ROWS) return;
  const bf16* Ap = A + (size_t)row * K;
  float acc = 0.f;
  for (int k = 0; k < K; k++) acc += b2f(Ap[k]) * ldin(B, (size_t)k * N + col, isb);
  float v = acc + ldin(bias, col, isb);
  if (EPI == 0) {
    out_b[(size_t)row * N + col] = f2b(v);
  } else if (EPI == 1) {
    int grow = row + row_base;
    int b_ = grow / 98, n = grow - b_ * 98;
    int batch = b_ >> 8, widx = b_ & 255;
    int tw = widx >> 6, hw = (widx >> 3) & 7, ww = widx & 7;
    int ti = n / 49, rr = n - ti * 49, hi = rr / 7, wi = rr - hi * 7;
    int t = (tw * 2 + ti + 1) & 7;
    int h = hw * 7 + hi + 3; if (h >= 56) h -= 56;
    int w = ww * 7 + wi + 3; if (w >= 56) w -= 56;
    size_t dstGlob = (size_t)batch * THW + (t * 56 + h) * 56 + w;
    size_t dstLoc = dstGlob - (size_t)tok_base;
    out_f[dstLoc * 128 + col] = ldin(resid_x, dstGlob * 128 + col, isb) + v;
  } else if (EPI == 2) {
    float gl = 0.5f * v * (1.f + erff(v * 0.70710678118654752f));
    out_b[(size_t)row * N + col] = f2b(gl);
  } else {
    float r = resid_f[(size_t)row * 128 + col] + v;
    stout(out_ext, ((size_t)(tok_base) + row) * 128 + col, r, isb);
  }
}

// ---------------- scalar attention: 1 thread per (window, head, query) ----------------
__global__ __launch_bounds__(256) void attn_s(const bf16* __restrict__ qkv,
    const void* __restrict__ rpb, bf16* __restrict__ outb, int wbase,
    const int* __restrict__ dflag) {
  int isb = *dflag;
  int idx = blockIdx.x * 256 + threadIdx.x;
  if (idx >= 256 * 4 * 98) return;
  int i = idx % 98; int hb = idx / 98;
  int head = hb & 3; int bl = hb >> 2;
  int bg = bl + wbase;
  const bf16* base = qkv + (size_t)bl * 98 * 384;

  float q[32];
  #pragma unroll
  for (int d = 0; d < 32; d++) q[d] = b2f(base[(size_t)i * 384 + head * 32 + d]) * SCALE_QK;

  int widx = bg & 255;
  int tw = widx >> 6, hw = (widx >> 3) & 7, ww = widx & 7;
  int ti = i / 49, rri = i - ti * 49, hi = rri / 7, wi = rri - hi * 7;
  int tgi = tw * 2 + ti, hgi = hw * 7 + hi, wgi = ww * 7 + wi;
  int ilab = ((tgi >= 6) + (tgi >= 7)) * 9 + ((hgi >= 49) + (hgi >= 53)) * 3 +
             ((wgi >= 49) + (wgi >= 53));

  float m = -1e30f, l = 0.f;
  float o[32];
  #pragma unroll
  for (int d = 0; d < 32; d++) o[d] = 0.f;

  for (int j = 0; j < 98; j++) {
    const bf16* kp = base + (size_t)j * 384 + 128 + head * 32;
    float s = 0.f;
    #pragma unroll
    for (int d = 0; d < 32; d++) s += q[d] * b2f(kp[d]);
    int tj = j / 49, rrj = j - tj * 49, hj = rrj / 7, wj = rrj - hj * 7;
    int tgj = tw * 2 + tj, hgj = hw * 7 + hj, wgj = ww * 7 + wj;
    int jlab = ((tgj >= 6) + (tgj >= 7)) * 9 + ((hgj >= 49) + (hgj >= 53)) * 3 +
               ((wgj >= 49) + (wgj >= 53));
    int bidx = (ti - tj + 1) * 169 + (hi - hj + 6) * 13 + (wi - wj + 6);
    s += ldin(rpb, (size_t)bidx * 4 + head, isb);
    if (ilab != jlab) s -= 100.f;

    float mn = fmaxf(m, s);
    float corr = expf(m - mn);
    float p = expf(s - mn);
    l = l * corr + p;
    const bf16* vp = base + (size_t)j * 384 + 256 + head * 32;
    #pragma unroll
    for (int d = 0; d < 32; d++) o[d] = o[d] * corr + p * b2f(vp[d]);
    m = mn;
  }
  float inv = 1.f / l;
  bf16* dst = outb + ((size_t)bl * 98 + i) * 128 + head * 32;
  #pragma unroll
  for (int d = 0; d < 32; d++) dst[d] = f2b(o[d] * inv);
}

extern "C" void kernel_launch(void* const* d_in, const int* in_sizes, int n_in,
                              void* d_out, int out_size, void* d_ws, size_t ws_size,
                              hipStream_t stream) {
  (void)in_sizes; (void)n_in; (void)out_size; (void)ws_size;
  const void* x      = d_in[0];
  const void* n1g    = d_in[1];
  const void* n1b    = d_in[2];
  const void* qkv_w  = d_in[3];
  const void* qkv_b  = d_in[4];
  const void* proj_w = d_in[5];
  const void* proj_b = d_in[6];
  const void* rpb    = d_in[7];
  const void* n2g    = d_in[8];
  const void* n2b    = d_in[9];
  const void* fc1_w  = d_in[10];
  const void* fc1_b  = d_in[11];
  const void* fc2_w  = d_in[12];
  const void* fc2_b  = d_in[13];

  char* ws = (char*)d_ws;
  int*   dflag = (int*)(ws + 0);                 // 256 B reserved
  bf16*  R0c  = (bf16*)(ws + 256);               //  6,422,528 B
  float* xmid = (float*)(ws + 256 + 6422528);    // 12,845,056 B
  bf16*  Zq   = (bf16*)(ws + 256 + 19267584);    // 25,690,112 B (qkv 19.3MB / hidden 25.7MB aliased)
  bf16*  Zh   = Zq;
  // peak ws usage ~= 45.0 MB

  detect_k<<<1, 1, 0, stream>>>(n1g, dflag);

  for (int c = 0; c < 8; c++) {
    const int row_base = c * CH_ROWS;
    const int tok_base = c * THW;
    const int wbase = c * 256;

    ln1_s<<<98, 256, 0, stream>>>(x, n1g, n1b, R0c, row_base, dflag);

    gemm_s<0, 128, 384><<<37632, 256, 0, stream>>>(R0c, qkv_w, qkv_b,
        Zq, nullptr, nullptr, nullptr, nullptr, 0, 0, dflag);

    attn_s<<<392, 256, 0, stream>>>(Zq, rpb, R0c, wbase, dflag);

    gemm_s<1, 128, 128><<<12544, 256, 0, stream>>>(R0c, proj_w, proj_b,
        nullptr, x, nullptr, xmid, nullptr, row_base, tok_base, dflag);

    ln2_s<<<98, 256, 0, stream>>>(xmid, n2g, n2b, R0c, dflag);

    gemm_s<2, 128, 512><<<50176, 256, 0, stream>>>(R0c, fc1_w, fc1_b,
        Zh, nullptr, nullptr, nullptr, nullptr, 0, 0, dflag);

    gemm_s<3, 512, 128><<<12544, 256, 0, stream>>>(Zh, fc2_w, fc2_b,
        nullptr, nullptr, xmid, nullptr, d_out, 0, tok_base, dflag);
  }
}

// Round 6
// 1137.243 us; speedup vs baseline: 9.3135x; 9.3135x over previous
//
#include <hip/hip_runtime.h>
#include <hip/hip_bf16.h>
#include <cmath>

using bf16 = __hip_bfloat16;
typedef __attribute__((ext_vector_type(8))) short short8;
typedef __attribute__((ext_vector_type(4))) float float4f;

#define THW 25088           // tokens per batch
#define CH_ROWS 25088       // 256 windows * 98 tokens per chunk (1 batch)
#define SCALE_QK 0.17677669529663687f

static __device__ __forceinline__ float4f mfma16(short8 a, short8 b, float4f c) {
  return __builtin_amdgcn_mfma_f32_16x16x32_bf16(a, b, c, 0, 0, 0);
}
static __device__ __forceinline__ short8 load8(const bf16* p) {
  return *reinterpret_cast<const short8*>(p);
}
static __device__ __forceinline__ float b2f(bf16 v) { return __bfloat162float(v); }
static __device__ __forceinline__ bf16 f2b(float v) { return __float2bfloat16(v); }
static __device__ __forceinline__ unsigned short f2bits(float v) {
  bf16 h = __float2bfloat16(v);
  unsigned short u; __builtin_memcpy(&u, &h, 2); return u;
}

// ---------------- weight transpose + bf16 cast: dst[n][k] = src[k][n] ----------------
__global__ __launch_bounds__(256) void transpose_k(const float* __restrict__ src,
                                                   bf16* __restrict__ dst, int K, int N) {
  int idx = blockIdx.x * 256 + threadIdx.x;
  if (idx < K * N) {
    int k = idx / N, n = idx - k * N;
    dst[(size_t)n * K + k] = f2b(src[idx]);
  }
}

// ---------------- LN1 + cyclic shift + window partition (one wave per token) --------
__global__ __launch_bounds__(256) void ln1_gather(const float* __restrict__ x,
    const float* __restrict__ g, const float* __restrict__ bt, bf16* __restrict__ xw,
    int row_base) {
  int gl = blockIdx.x * 4 + (threadIdx.x >> 6);   // local windowed row
  int gid = gl + row_base;
  int lane = threadIdx.x & 63;
  int b_ = gid / 98, n = gid - b_ * 98;
  int batch = b_ >> 8, widx = b_ & 255;
  int tw = widx >> 6, hw = (widx >> 3) & 7, ww = widx & 7;
  int ti = n / 49, rr = n - ti * 49, hi = rr / 7, wi = rr - hi * 7;
  int t = (tw * 2 + ti + 1) & 7;
  int h = hw * 7 + hi + 3; if (h >= 56) h -= 56;
  int w = ww * 7 + wi + 3; if (w >= 56) w -= 56;
  const float2* src = reinterpret_cast<const float2*>(
      x + ((size_t)batch * THW + (t * 56 + h) * 56 + w) * 128);
  float2 v = src[lane];
  float s = v.x + v.y, ss = v.x * v.x + v.y * v.y;
  #pragma unroll
  for (int m = 1; m < 64; m <<= 1) { s += __shfl_xor(s, m); ss += __shfl_xor(ss, m); }
  float mu = s * (1.f / 128.f);
  float var = ss * (1.f / 128.f) - mu * mu;
  float rs = rsqrtf(var + 1e-5f);
  float2 gp = reinterpret_cast<const float2*>(g)[lane];
  float2 bp = reinterpret_cast<const float2*>(bt)[lane];
  float o0 = (v.x - mu) * rs * gp.x + bp.x;
  float o1 = (v.y - mu) * rs * gp.y + bp.y;
  reinterpret_cast<unsigned int*>(xw + (size_t)gl * 128)[lane] =
      (unsigned int)f2bits(o0) | ((unsigned int)f2bits(o1) << 16);
}

// ---------------- LN2 (fp32 in, bf16 out, local rows) ----------------
__global__ __launch_bounds__(256) void ln2_k(const float* __restrict__ xm,
    const float* __restrict__ g, const float* __restrict__ bt, bf16* __restrict__ out) {
  int gl = blockIdx.x * 4 + (threadIdx.x >> 6);
  int lane = threadIdx.x & 63;
  const float2* src = reinterpret_cast<const float2*>(xm + (size_t)gl * 128);
  float2 v = src[lane];
  float s = v.x + v.y, ss = v.x * v.x + v.y * v.y;
  #pragma unroll
  for (int m = 1; m < 64; m <<= 1) { s += __shfl_xor(s, m); ss += __shfl_xor(ss, m); }
  float mu = s * (1.f / 128.f);
  float var = ss * (1.f / 128.f) - mu * mu;
  float rs = rsqrtf(var + 1e-5f);
  float2 gp = reinterpret_cast<const float2*>(g)[lane];
  float2 bp = reinterpret_cast<const float2*>(bt)[lane];
  float o0 = (v.x - mu) * rs * gp.x + bp.x;
  float o1 = (v.y - mu) * rs * gp.y + bp.y;
  reinterpret_cast<unsigned int*>(out + (size_t)gl * 128)[lane] =
      (unsigned int)f2bits(o0) | ((unsigned int)f2bits(o1) << 16);
}

// ---------------- MFMA GEMM, Bt is [N][K] row-major bf16, bias fp32 ----------------
// EPI: 0=bias+store bf16, 1=proj scatter (+fp32 x residual -> fp32 xmid),
//      2=bias+GELU store bf16, 3=bias + fp32 residual -> fp32 out
template<int EPI, int K>
__global__ __launch_bounds__(256) void gemm_bt(const bf16* __restrict__ A,
    const bf16* __restrict__ Bt, const float* __restrict__ bias,
    bf16* __restrict__ out_b, const float* __restrict__ resid_x,
    const float* __restrict__ resid_f, float* __restrict__ out_f,
    int row_base, int tok_base) {
  const int lane = threadIdx.x & 63, wave = threadIdx.x >> 6;
  const int l15 = lane & 15, lq = lane >> 4;
  const int wm = wave & 1, wn = wave >> 1;
  const int row0 = blockIdx.x * 64 + wm * 32;
  const int col0 = blockIdx.y * 128 + wn * 64;
  const int ldC = gridDim.y * 128;
  const bf16* Ap = A + (size_t)(row0 + l15) * K + lq * 8;
  const bf16* Bp = Bt + (size_t)(col0 + l15) * K + lq * 8;
  float4f acc[2][4];
  #pragma unroll
  for (int mt = 0; mt < 2; mt++)
    #pragma unroll
    for (int nt = 0; nt < 4; nt++) acc[mt][nt] = (float4f){0.f, 0.f, 0.f, 0.f};

  #pragma unroll
  for (int k0 = 0; k0 < K; k0 += 32) {
    short8 a0 = load8(Ap + k0);
    short8 a1 = load8(Ap + 16 * K + k0);
    #pragma unroll
    for (int nt = 0; nt < 4; nt++) {
      short8 b = load8(Bp + nt * 16 * K + k0);
      acc[0][nt] = mfma16(a0, b, acc[0][nt]);
      acc[1][nt] = mfma16(a1, b, acc[1][nt]);
    }
  }

  #pragma unroll
  for (int mt = 0; mt < 2; mt++) {
    #pragma unroll
    for (int r = 0; r < 4; r++) {
      int row = row0 + mt * 16 + lq * 4 + r;      // local row
      size_t dstLoc = 0, dstGlob = 0;
      if (EPI == 1) {
        int grow = row + row_base;
        int b_ = grow / 98, n = grow - b_ * 98;
        int batch = b_ >> 8, widx = b_ & 255;
        int tw = widx >> 6, hw = (widx >> 3) & 7, ww = widx & 7;
        int ti = n / 49, rr = n - ti * 49, hi = rr / 7, wi = rr - hi * 7;
        int t = (tw * 2 + ti + 1) & 7;
        int h = hw * 7 + hi + 3; if (h >= 56) h -= 56;
        int w = ww * 7 + wi + 3; if (w >= 56) w -= 56;
        dstGlob = (size_t)batch * THW + (t * 56 + h) * 56 + w;
        dstLoc = dstGlob - (size_t)tok_base;
      }
      #pragma unroll
      for (int nt = 0; nt < 4; nt++) {
        int col = col0 + nt * 16 + l15;
        float v = acc[mt][nt][r] + bias[col];
        if (EPI == 0) {
          out_b[(size_t)row * ldC + col] = f2b(v);
        } else if (EPI == 1) {
          out_f[dstLoc * 128 + col] = resid_x[dstGlob * 128 + col] + v;
        } else if (EPI == 2) {
          float gl = 0.5f * v * (1.f + erff(v * 0.70710678118654752f));
          out_b[(size_t)row * ldC + col] = f2b(gl);
        } else {
          out_f[(size_t)row * 128 + col] = resid_f[(size_t)row * 128 + col] + v;
        }
      }
    }
  }
}

// ---------------- attention: one wave per (window, head, 16-row block) ----------------
__global__ __launch_bounds__(256) void attn_k(const bf16* __restrict__ qkv,
    const float* __restrict__ rpb, bf16* __restrict__ outb, int wbase) {
  __shared__ __align__(16) unsigned short Pl[4][16][136];
  const int wave = threadIdx.x >> 6, lane = threadIdx.x & 63;
  const int l15 = lane & 15, lq = lane >> 4;
  int g = blockIdx.x * 4 + wave;           // 0..7167 per chunk
  int rb = g % 7; int bh = g / 7; int head = bh & 3; int bl = bh >> 2;
  int bg = bl + wbase;
  int q0 = rb * 16;
  const bf16* base = qkv + (size_t)bl * 98 * 384;
  const unsigned short* base_u = reinterpret_cast<const unsigned short*>(base);

  // Q fragment (A operand): A[m=l15][k=lq*8+j]
  int qrow = q0 + l15; if (qrow > 97) qrow = 97;
  short8 aq = load8(base + (size_t)qrow * 384 + head * 32 + lq * 8);

  // S = Q K^T : 7 col-tiles, one MFMA each (K=HD=32)
  float4f s[7];
  #pragma unroll
  for (int t = 0; t < 7; t++) {
    int kr = t * 16 + l15; if (kr > 97) kr = 97;
    short8 kb = load8(base + (size_t)kr * 384 + 128 + head * 32 + lq * 8);
    s[t] = mfma16(aq, kb, (float4f){0.f, 0.f, 0.f, 0.f});
  }

  int widx = bg & 255;
  int tw = widx >> 6, hw = (widx >> 3) & 7, ww = widx & 7;
  int iti[4], ihi[4], iwi[4], ilab[4];
  #pragma unroll
  for (int r = 0; r < 4; r++) {
    int i = q0 + lq * 4 + r; if (i > 97) i = 97;
    int ti = i / 49, rr = i - ti * 49, hi = rr / 7, wi = rr - hi * 7;
    iti[r] = ti; ihi[r] = hi; iwi[r] = wi;
    int tg = tw * 2 + ti, hg = hw * 7 + hi, wg = ww * 7 + wi;
    ilab[r] = ((tg >= 6) + (tg >= 7)) * 9 + ((hg >= 49) + (hg >= 53)) * 3 +
              ((wg >= 49) + (wg >= 53));
  }

  float pv[7][4];
  #pragma unroll
  for (int t = 0; t < 7; t++) {
    int j = t * 16 + l15;
    bool jvalid = (j < 98); int jc = jvalid ? j : 97;
    int tj = jc / 49, rr = jc - tj * 49, hj = rr / 7, wj = rr - hj * 7;
    int tg = tw * 2 + tj, hg = hw * 7 + hj, wg = ww * 7 + wj;
    int jlab = ((tg >= 6) + (tg >= 7)) * 9 + ((hg >= 49) + (hg >= 53)) * 3 +
               ((wg >= 49) + (wg >= 53));
    #pragma unroll
    for (int r = 0; r < 4; r++) {
      int idx = (iti[r] - tj + 1) * 169 + (ihi[r] - hj + 6) * 13 + (iwi[r] - wj + 6);
      float v = s[t][r] * SCALE_QK + rpb[idx * 4 + head];
      if (ilab[r] != jlab) v -= 100.f;
      if (!jvalid) v = -30000.f;
      pv[t][r] = v;
    }
  }

  // exact softmax over the full 112-col row held in registers
  #pragma unroll
  for (int r = 0; r < 4; r++) {
    float m = pv[0][r];
    #pragma unroll
    for (int t = 1; t < 7; t++) m = fmaxf(m, pv[t][r]);
    #pragma unroll
    for (int d = 1; d < 16; d <<= 1) m = fmaxf(m, __shfl_xor(m, d));
    float sum = 0.f;
    #pragma unroll
    for (int t = 0; t < 7; t++) { float p = __expf(pv[t][r] - m); pv[t][r] = p; sum += p; }
    #pragma unroll
    for (int d = 1; d < 16; d <<= 1) sum += __shfl_xor(sum, d);
    float inv = 1.f / sum;
    int prow = lq * 4 + r;
    #pragma unroll
    for (int t = 0; t < 7; t++) Pl[wave][prow][t * 16 + l15] = f2bits(pv[t][r] * inv);
    Pl[wave][prow][112 + l15] = 0;   // zero-pad cols 112..127
  }

  __syncthreads();

  // O = P V : K padded to 128 (P zero there)
  float4f o[2];
  o[0] = (float4f){0.f, 0.f, 0.f, 0.f};
  o[1] = (float4f){0.f, 0.f, 0.f, 0.f};
  #pragma unroll
  for (int ks = 0; ks < 4; ks++) {
    short8 ap = *reinterpret_cast<const short8*>(&Pl[wave][l15][ks * 32 + lq * 8]);
    #pragma unroll
    for (int dt = 0; dt < 2; dt++) {
      short8 vb;
      #pragma unroll
      for (int j = 0; j < 8; j++) {
        int vr = ks * 32 + lq * 8 + j; if (vr > 97) vr = 97;
        vb[j] = (short)base_u[(size_t)vr * 384 + 256 + head * 32 + dt * 16 + l15];
      }
      o[dt] = mfma16(ap, vb, o[dt]);
    }
  }
  #pragma unroll
  for (int dt = 0; dt < 2; dt++) {
    #pragma unroll
    for (int r = 0; r < 4; r++) {
      int row = q0 + lq * 4 + r;
      if (row < 98)
        outb[((size_t)bl * 98 + row) * 128 + head * 32 + dt * 16 + l15] = f2b(o[dt][r]);
    }
  }
}

extern "C" void kernel_launch(void* const* d_in, const int* in_sizes, int n_in,
                              void* d_out, int out_size, void* d_ws, size_t ws_size,
                              hipStream_t stream) {
  (void)in_sizes; (void)n_in; (void)out_size; (void)ws_size;
  const float* x      = (const float*)d_in[0];
  const float* n1g    = (const float*)d_in[1];
  const float* n1b    = (const float*)d_in[2];
  const float* qkv_w  = (const float*)d_in[3];
  const float* qkv_b  = (const float*)d_in[4];
  const float* proj_w = (const float*)d_in[5];
  const float* proj_b = (const float*)d_in[6];
  const float* rpb    = (const float*)d_in[7];
  const float* n2g    = (const float*)d_in[8];
  const float* n2b    = (const float*)d_in[9];
  const float* fc1_w  = (const float*)d_in[10];
  const float* fc1_b  = (const float*)d_in[11];
  const float* fc2_w  = (const float*)d_in[12];
  const float* fc2_b  = (const float*)d_in[13];
  float* out = (float*)d_out;

  char* ws = (char*)d_ws;
  bf16* bt_qkv  = (bf16*)(ws + 0);        //  98304 B
  bf16* bt_proj = (bf16*)(ws + 98304);    //  32768 B
  bf16* bt_fc1  = (bf16*)(ws + 131072);   // 131072 B
  bf16* bt_fc2  = (bf16*)(ws + 262144);   // 131072 B
  bf16*  R0c  = (bf16*)(ws + 393216);                  //  6,422,528 B
  float* xmid = (float*)(ws + 393216 + 6422528);       // 12,845,056 B
  bf16*  Zq   = (bf16*)(ws + 393216 + 19267584);       // 25.69 MB (qkv/hidden aliased)
  bf16*  Zh   = Zq;
  // peak ws ~= 45.4 MB (proven safe in round 5)

  transpose_k<<<192, 256, 0, stream>>>(qkv_w, bt_qkv, 128, 384);
  transpose_k<<<64,  256, 0, stream>>>(proj_w, bt_proj, 128, 128);
  transpose_k<<<256, 256, 0, stream>>>(fc1_w, bt_fc1, 128, 512);
  transpose_k<<<256, 256, 0, stream>>>(fc2_w, bt_fc2, 512, 128);

  for (int c = 0; c < 8; c++) {
    const int row_base = c * CH_ROWS;
    const int tok_base = c * THW;
    const int wbase = c * 256;

    // LN1 + shift + partition -> R0c [CH_ROWS x 128] bf16
    ln1_gather<<<6272, 256, 0, stream>>>(x, n1g, n1b, R0c, row_base);

    // qkv -> Zq [CH_ROWS x 384] bf16
    gemm_bt<0, 128><<<dim3(392, 3), 256, 0, stream>>>(R0c, bt_qkv, qkv_b,
        Zq, nullptr, nullptr, nullptr, 0, 0);

    // attention -> R0c (windowed order) bf16
    attn_k<<<1792, 256, 0, stream>>>(Zq, rpb, R0c, wbase);

    // proj + window-reverse/unshift scatter + residual(x) -> xmid fp32 (natural)
    gemm_bt<1, 128><<<dim3(392, 1), 256, 0, stream>>>(R0c, bt_proj, proj_b,
        nullptr, x, nullptr, xmid, row_base, tok_base);

    // LN2 -> R0c bf16 (natural order)
    ln2_k<<<6272, 256, 0, stream>>>(xmid, n2g, n2b, R0c);

    // fc1 + GELU -> Zh [CH_ROWS x 512] bf16
    gemm_bt<2, 128><<<dim3(392, 4), 256, 0, stream>>>(R0c, bt_fc1, fc1_b,
        Zh, nullptr, nullptr, nullptr, 0, 0);

    // fc2 + residual(xmid) -> fp32 out chunk
    gemm_bt<3, 512><<<dim3(392, 1), 256, 0, stream>>>(Zh, bt_fc2, fc2_b,
        nullptr, nullptr, xmid, out + (size_t)tok_base * 128, 0, 0);
  }
}